// Round 1
// baseline (56.026 us; speedup 1.0000x reference)
//
#include <hip/hip_runtime.h>

// PoolingAggregator: out[b,g] = mean over {t : segment_ids[t]==g} of features[b, flat_indices[t]]
// B=512, N=10000, G=2048, T=131072 (derived from in_sizes/out_size where possible).
//
// Strategy:
//   1) transpose features (B,N) -> featT (N,B) so each gathered column is a
//      contiguous 2KB row (coalesced float2 loads).
//   2) one block per group g: binary-search [s,e) in sorted segment_ids,
//      stage indices in LDS, accumulate the referenced rows, divide by count,
//      write coalesced into outT (G,B).
//   3) transpose outT (G,B) -> out (B,G).

#define TT 32  // transpose tile

__global__ __launch_bounds__(256) void transpose_f32(const float* __restrict__ in,
                                                     float* __restrict__ out,
                                                     int rows, int cols) {
    // in: rows x cols, out: cols x rows
    __shared__ float tile[TT][TT + 1];
    int c0 = blockIdx.x * TT;
    int r0 = blockIdx.y * TT;
    int x = threadIdx.x;  // 0..31
    #pragma unroll
    for (int yy = threadIdx.y; yy < TT; yy += 8) {
        int r = r0 + yy, c = c0 + x;
        tile[yy][x] = (r < rows && c < cols) ? in[(long)r * cols + c] : 0.0f;
    }
    __syncthreads();
    #pragma unroll
    for (int yy = threadIdx.y; yy < TT; yy += 8) {
        int oc = c0 + yy, orr = r0 + x;
        if (oc < cols && orr < rows) out[(long)oc * rows + orr] = tile[x][yy];
    }
}

// One block (256 threads) per group. B must be 512 (2 floats per thread).
__global__ __launch_bounds__(256) void group_mean_kernel(
    const float* __restrict__ featT,          // (N, B)
    const int* __restrict__ flat_indices,     // (T,)
    const int* __restrict__ segment_ids,      // (T,) sorted
    float* __restrict__ outT,                 // (G, B)
    int T, int B) {
    const int g = blockIdx.x;
    const int tid = threadIdx.x;
    __shared__ int sb[2];
    __shared__ int s_idx[256];

    if (tid < 2) {
        // lower_bound(segment_ids, g + tid)
        int target = g + tid;
        int lo = 0, hi = T;
        while (lo < hi) {
            int mid = (lo + hi) >> 1;
            if (segment_ids[mid] < target) lo = mid + 1; else hi = mid;
        }
        sb[tid] = lo;
    }
    __syncthreads();
    const int s = sb[0], e = sb[1];
    const int cnt = e - s;

    const int halfB = B >> 1;  // 256: thread tid owns float2 column tid
    const float2* __restrict__ featT2 = (const float2*)featT;
    float2 acc = make_float2(0.0f, 0.0f);

    for (int base = s; base < e; base += 256) {
        int k = base + tid;
        if (k < e) s_idx[tid - 0] = flat_indices[k];
        __syncthreads();
        int m = min(256, e - base);
        int j = 0;
        for (; j + 4 <= m; j += 4) {
            int i0 = s_idx[j + 0];
            int i1 = s_idx[j + 1];
            int i2 = s_idx[j + 2];
            int i3 = s_idx[j + 3];
            float2 v0 = featT2[(long)i0 * halfB + tid];
            float2 v1 = featT2[(long)i1 * halfB + tid];
            float2 v2 = featT2[(long)i2 * halfB + tid];
            float2 v3 = featT2[(long)i3 * halfB + tid];
            acc.x += v0.x; acc.y += v0.y;
            acc.x += v1.x; acc.y += v1.y;
            acc.x += v2.x; acc.y += v2.y;
            acc.x += v3.x; acc.y += v3.y;
        }
        for (; j < m; ++j) {
            int i0 = s_idx[j];
            float2 v = featT2[(long)i0 * halfB + tid];
            acc.x += v.x; acc.y += v.y;
        }
        __syncthreads();
    }

    float inv = 1.0f / (float)(cnt > 0 ? cnt : 1);
    float2 r = make_float2(acc.x * inv, acc.y * inv);
    ((float2*)outT)[(long)g * halfB + tid] = r;
}

// Fallback (no workspace): direct strided gather, uncoalesced but correct.
__global__ __launch_bounds__(256) void group_mean_direct(
    const float* __restrict__ feat,           // (B, N)
    const int* __restrict__ flat_indices,
    const int* __restrict__ segment_ids,
    float* __restrict__ out,                  // (B, G)
    int T, int B, int N, int G) {
    const int g = blockIdx.x;
    const int tid = threadIdx.x;
    __shared__ int sb[2];
    __shared__ int s_idx[256];
    if (tid < 2) {
        int target = g + tid;
        int lo = 0, hi = T;
        while (lo < hi) {
            int mid = (lo + hi) >> 1;
            if (segment_ids[mid] < target) lo = mid + 1; else hi = mid;
        }
        sb[tid] = lo;
    }
    __syncthreads();
    const int s = sb[0], e = sb[1];
    const int cnt = e - s;
    int b0 = tid * 2, b1 = tid * 2 + 1;
    float a0 = 0.f, a1 = 0.f;
    for (int base = s; base < e; base += 256) {
        int k = base + tid;
        if (k < e) s_idx[tid] = flat_indices[k];
        __syncthreads();
        int m = min(256, e - base);
        for (int j = 0; j < m; ++j) {
            int idx = s_idx[j];
            if (b0 < B) a0 += feat[(long)b0 * N + idx];
            if (b1 < B) a1 += feat[(long)b1 * N + idx];
        }
        __syncthreads();
    }
    float inv = 1.0f / (float)(cnt > 0 ? cnt : 1);
    if (b0 < B) out[(long)b0 * G + g] = a0 * inv;
    if (b1 < B) out[(long)b1 * G + g] = a1 * inv;
}

extern "C" void kernel_launch(void* const* d_in, const int* in_sizes, int n_in,
                              void* d_out, int out_size, void* d_ws, size_t ws_size,
                              hipStream_t stream) {
    const float* feat          = (const float*)d_in[0];
    const int*   flat_indices  = (const int*)d_in[1];
    const int*   segment_ids   = (const int*)d_in[2];
    float*       out           = (float*)d_out;

    const int B = 512;
    const int N = in_sizes[0] / B;      // 10000
    const int T = in_sizes[1];          // 131072
    const int G = out_size / B;         // 2048

    size_t need = ((size_t)N * B + (size_t)G * B) * sizeof(float);
    if (ws_size >= need && (B % 2) == 0 && B == 512) {
        float* featT = (float*)d_ws;                  // (N, B)
        float* outT  = featT + (size_t)N * B;         // (G, B)

        dim3 blk(32, 8);
        dim3 g1((N + TT - 1) / TT, (B + TT - 1) / TT);
        transpose_f32<<<g1, blk, 0, stream>>>(feat, featT, B, N);

        group_mean_kernel<<<G, 256, 0, stream>>>(featT, flat_indices, segment_ids,
                                                 outT, T, B);

        dim3 g2((B + TT - 1) / TT, (G + TT - 1) / TT);
        transpose_f32<<<g2, blk, 0, stream>>>(outT, out, G, B);
    } else {
        group_mean_direct<<<G, 256, 0, stream>>>(feat, flat_indices, segment_ids,
                                                 out, T, B, N, G);
    }
}

// Round 2
// 42.073 us; speedup vs baseline: 1.3316x; 1.3316x over previous
//
#include <hip/hip_runtime.h>

// PoolingAggregator: out[b,g] = mean over {t : segment_ids[t]==g} of features[b, flat_indices[t]]
// B=512, N=10000, G=2048, T=131072.
//
// Pipeline:
//   k0: group offsets[g] = lower_bound(segment_ids, g) for g in [0..G]  (parallel binary searches)
//   k1: transpose features (B,N) -> featT (N,B)   [gathered rows become contiguous]
//   k2: gather+mean, one WAVE per (group, B-chunk). chunk = blockIdx%8 pins each
//       2.56MB featT column-slice to one XCD's L2 -> gather served at L2 BW.
//       16 lanes x float4 cover 64 floats of B; 4 index-slots reduced via shfl_xor.
//       No LDS, no barriers, no per-block binary search.
//   k3: transpose outT (G,B) -> out (B,G)

#define TT 32

__global__ __launch_bounds__(256) void pa_transpose_f32(const float* __restrict__ in,
                                                        float* __restrict__ out,
                                                        int rows, int cols) {
    __shared__ float tile[TT][TT + 1];
    int c0 = blockIdx.x * TT;
    int r0 = blockIdx.y * TT;
    int x = threadIdx.x;
    #pragma unroll
    for (int yy = threadIdx.y; yy < TT; yy += 8) {
        int r = r0 + yy, c = c0 + x;
        tile[yy][x] = (r < rows && c < cols) ? in[(long)r * cols + c] : 0.0f;
    }
    __syncthreads();
    #pragma unroll
    for (int yy = threadIdx.y; yy < TT; yy += 8) {
        int oc = c0 + yy, orr = r0 + x;
        if (oc < cols && orr < rows) out[(long)oc * rows + orr] = tile[x][yy];
    }
}

__global__ __launch_bounds__(256) void pa_offsets(const int* __restrict__ segment_ids,
                                                  int* __restrict__ offs,
                                                  int T, int G) {
    int g = blockIdx.x * blockDim.x + threadIdx.x;
    if (g > G) return;
    int lo = 0, hi = T;
    while (lo < hi) {
        int mid = (lo + hi) >> 1;
        if (segment_ids[mid] < g) lo = mid + 1; else hi = mid;
    }
    offs[g] = lo;
}

// grid = (G/4) * 8 blocks, 256 threads (4 waves). Wave w of block b handles
// group (b/8)*4 + w, B-chunk c = b%8 (64 floats = 16 float4 lanes).
__global__ __launch_bounds__(256) void pa_group_mean(
    const float* __restrict__ featT,        // (N, 512)
    const int* __restrict__ flat_indices,   // (T,)
    const int* __restrict__ offs,           // (G+1,)
    float* __restrict__ outT) {             // (G, 512)
    const int chunk = blockIdx.x & 7;
    const int wave  = threadIdx.x >> 6;
    const int g     = (blockIdx.x >> 3) * 4 + wave;
    const int lane  = threadIdx.x & 63;
    const int lane_b = lane & 15;   // which float4 of the 64-float chunk
    const int slot   = lane >> 4;   // 0..3 index-parallel

    const int s = offs[g];
    const int e = offs[g + 1];
    const int cnt = e - s;

    const float4* __restrict__ fp =
        (const float4*)featT + (size_t)chunk * 16 + lane_b;  // row stride 128 float4

    float ax0 = 0.f, ay0 = 0.f, az0 = 0.f, aw0 = 0.f;
    float ax1 = 0.f, ay1 = 0.f, az1 = 0.f, aw1 = 0.f;
    float ax2 = 0.f, ay2 = 0.f, az2 = 0.f, aw2 = 0.f;
    float ax3 = 0.f, ay3 = 0.f, az3 = 0.f, aw3 = 0.f;

    int j = s + slot;
    for (; j + 12 < e; j += 16) {
        int i0 = flat_indices[j];
        int i1 = flat_indices[j + 4];
        int i2 = flat_indices[j + 8];
        int i3 = flat_indices[j + 12];
        float4 v0 = fp[(size_t)i0 * 128];
        float4 v1 = fp[(size_t)i1 * 128];
        float4 v2 = fp[(size_t)i2 * 128];
        float4 v3 = fp[(size_t)i3 * 128];
        ax0 += v0.x; ay0 += v0.y; az0 += v0.z; aw0 += v0.w;
        ax1 += v1.x; ay1 += v1.y; az1 += v1.z; aw1 += v1.w;
        ax2 += v2.x; ay2 += v2.y; az2 += v2.z; aw2 += v2.w;
        ax3 += v3.x; ay3 += v3.y; az3 += v3.z; aw3 += v3.w;
    }
    for (; j < e; j += 4) {
        float4 v = fp[(size_t)flat_indices[j] * 128];
        ax0 += v.x; ay0 += v.y; az0 += v.z; aw0 += v.w;
    }
    float ax = (ax0 + ax1) + (ax2 + ax3);
    float ay = (ay0 + ay1) + (ay2 + ay3);
    float az = (az0 + az1) + (az2 + az3);
    float aw = (aw0 + aw1) + (aw2 + aw3);

    // reduce across the 4 slots (lane bits 4,5)
    ax += __shfl_xor(ax, 16); ax += __shfl_xor(ax, 32);
    ay += __shfl_xor(ay, 16); ay += __shfl_xor(ay, 32);
    az += __shfl_xor(az, 16); az += __shfl_xor(az, 32);
    aw += __shfl_xor(aw, 16); aw += __shfl_xor(aw, 32);

    if (slot == 0) {
        float inv = 1.0f / fmaxf((float)cnt, 1.0f);
        float4 r = make_float4(ax * inv, ay * inv, az * inv, aw * inv);
        ((float4*)outT)[(size_t)g * 128 + chunk * 16 + lane_b] = r;
    }
}

// Fallback for unexpected shapes (kept from R0, correct but slow).
__global__ __launch_bounds__(256) void pa_group_mean_direct(
    const float* __restrict__ feat, const int* __restrict__ flat_indices,
    const int* __restrict__ segment_ids, float* __restrict__ out,
    int T, int B, int N, int G) {
    const int g = blockIdx.x;
    const int tid = threadIdx.x;
    __shared__ int sb[2];
    __shared__ int s_idx[256];
    if (tid < 2) {
        int target = g + tid;
        int lo = 0, hi = T;
        while (lo < hi) {
            int mid = (lo + hi) >> 1;
            if (segment_ids[mid] < target) lo = mid + 1; else hi = mid;
        }
        sb[tid] = lo;
    }
    __syncthreads();
    const int s = sb[0], e = sb[1];
    const int cnt = e - s;
    int b0 = tid * 2, b1 = tid * 2 + 1;
    float a0 = 0.f, a1 = 0.f;
    for (int base = s; base < e; base += 256) {
        int k = base + tid;
        if (k < e) s_idx[tid] = flat_indices[k];
        __syncthreads();
        int m = min(256, e - base);
        for (int jj = 0; jj < m; ++jj) {
            int idx = s_idx[jj];
            if (b0 < B) a0 += feat[(long)b0 * N + idx];
            if (b1 < B) a1 += feat[(long)b1 * N + idx];
        }
        __syncthreads();
    }
    float inv = 1.0f / (float)(cnt > 0 ? cnt : 1);
    if (b0 < B) out[(long)b0 * G + g] = a0 * inv;
    if (b1 < B) out[(long)b1 * G + g] = a1 * inv;
}

extern "C" void kernel_launch(void* const* d_in, const int* in_sizes, int n_in,
                              void* d_out, int out_size, void* d_ws, size_t ws_size,
                              hipStream_t stream) {
    const float* feat          = (const float*)d_in[0];
    const int*   flat_indices  = (const int*)d_in[1];
    const int*   segment_ids   = (const int*)d_in[2];
    float*       out           = (float*)d_out;

    const int B = 512;
    const int N = in_sizes[0] / B;      // 10000
    const int T = in_sizes[1];          // 131072
    const int G = out_size / B;         // 2048

    size_t need = ((size_t)N * B + (size_t)G * B) * sizeof(float) + (size_t)(G + 1) * sizeof(int);
    if (ws_size >= need && B == 512 && (G % 4) == 0) {
        float* featT = (float*)d_ws;                   // (N, 512)
        float* outT  = featT + (size_t)N * B;          // (G, 512)
        int*   offs  = (int*)(outT + (size_t)G * B);   // (G+1,)

        pa_offsets<<<(G + 256) / 256, 256, 0, stream>>>(segment_ids, offs, T, G);

        dim3 blk(32, 8);
        dim3 g1((N + TT - 1) / TT, (B + TT - 1) / TT);
        pa_transpose_f32<<<g1, blk, 0, stream>>>(feat, featT, B, N);

        pa_group_mean<<<(G / 4) * 8, 256, 0, stream>>>(featT, flat_indices, offs, outT);

        dim3 g2((B + TT - 1) / TT, (G + TT - 1) / TT);
        pa_transpose_f32<<<g2, blk, 0, stream>>>(outT, out, G, B);
    } else {
        pa_group_mean_direct<<<G, 256, 0, stream>>>(feat, flat_indices, segment_ids,
                                                    out, T, B, N, G);
    }
}

// Round 3
// 33.662 us; speedup vs baseline: 1.6644x; 1.2498x over previous
//
#include <hip/hip_runtime.h>

// PoolingAggregator: out[b,g] = mean over {t : segment_ids[t]==g} of feat[b, flat_indices[t]]
// B=512, N=10000, G=2048, T=131072.
//
// Pipeline (3 kernels):
//   k0: offs[g] = lower_bound(segment_ids, g) via linear boundary scan (T threads)
//   k1: transpose+convert feat (B,N) f32 -> featT (N,512) bf16  [row gather becomes
//       contiguous 1KB, traffic halved vs f32]
//   k2: gather+mean: one WAVE per (group, 64-float B-chunk); chunk = blockIdx%8 pins
//       each 1.28MB featT slice to one XCD L2. 8 lanes x 16B cover the chunk,
//       8 index-slots, unroll 4 -> 32 indices in flight. shfl_xor reduce, then
//       LDS 4x64 tile -> direct coalesced store to out (B,G). No final transpose.

__device__ __forceinline__ unsigned bf16rne(float f) {
    unsigned u = __float_as_uint(f);
    return (u + 0x7fffu + ((u >> 16) & 1u)) >> 16;
}

__global__ __launch_bounds__(256) void pa_offsets_linear(const int* __restrict__ seg,
                                                         int* __restrict__ offs,
                                                         int T, int G) {
    int t = blockIdx.x * blockDim.x + threadIdx.x;
    if (t >= T) return;
    int cur  = seg[t];
    int prev = (t == 0) ? -1 : seg[t - 1];
    for (int g = prev + 1; g <= cur; ++g) offs[g] = t;
    if (t == T - 1) {
        for (int g = cur + 1; g <= G; ++g) offs[g] = T;
    }
}

// feat (B=512, N) f32 -> featT (N, 512) bf16. blockDim (32,8), grid (ceil(N/32), 8).
#define TRN 32
#define TRB 64
__global__ __launch_bounds__(256) void pa_transpose_bf16(const float* __restrict__ in,
                                                         unsigned short* __restrict__ outT,
                                                         int N) {
    __shared__ float tile[TRB][TRN + 1];
    int n0 = blockIdx.x * TRN;
    int b0 = blockIdx.y * TRB;
    int x = threadIdx.x;  // 0..31 -> n on read, uint-col on write
    #pragma unroll
    for (int yy = threadIdx.y; yy < TRB; yy += 8) {
        int n = n0 + x;
        tile[yy][x] = (n < N) ? in[(size_t)(b0 + yy) * N + n] : 0.0f;
    }
    __syncthreads();
    unsigned* outu = (unsigned*)outT;
    #pragma unroll
    for (int yy = threadIdx.y; yy < TRN; yy += 8) {
        int n = n0 + yy;
        if (n >= N) continue;
        float f0 = tile[2 * x][yy];
        float f1 = tile[2 * x + 1][yy];
        unsigned u = bf16rne(f0) | (bf16rne(f1) << 16);
        outu[(size_t)n * 256 + (b0 >> 1) + x] = u;
    }
}

// grid = (G/4)*8 blocks, 256 threads (4 waves). Wave w of block b: group (b>>3)*4+w,
// B-chunk c = b&7 (64 floats = 8 lanes x 8 bf16). slot = lane>>3 (8 index-parallel).
__global__ __launch_bounds__(256) void pa_gather_mean_bf16(
    const unsigned short* __restrict__ featT,  // (N, 512) bf16
    const int* __restrict__ idxs,              // (T,)
    const int* __restrict__ offs,              // (G+1,)
    float* __restrict__ out,                   // (B, G)
    int G) {
    const int chunk = blockIdx.x & 7;
    const int wave  = threadIdx.x >> 6;
    const int g     = (blockIdx.x >> 3) * 4 + wave;
    const int lane  = threadIdx.x & 63;
    const int lane_b = lane & 7;
    const int slot   = lane >> 3;

    const int s = offs[g];
    const int e = offs[g + 1];
    const int cnt = e - s;

    // row stride = 512 bf16 = 64 uint4; lane covers 8 bf16 = 1 uint4
    const uint4* __restrict__ fp = (const uint4*)featT + chunk * 8 + lane_b;

    float a0 = 0.f, a1 = 0.f, a2 = 0.f, a3 = 0.f,
          a4 = 0.f, a5 = 0.f, a6 = 0.f, a7 = 0.f;

#define ACC8(v)                                                        \
    do {                                                               \
        a0 += __uint_as_float((v).x << 16);                            \
        a1 += __uint_as_float((v).x & 0xffff0000u);                    \
        a2 += __uint_as_float((v).y << 16);                            \
        a3 += __uint_as_float((v).y & 0xffff0000u);                    \
        a4 += __uint_as_float((v).z << 16);                            \
        a5 += __uint_as_float((v).z & 0xffff0000u);                    \
        a6 += __uint_as_float((v).w << 16);                            \
        a7 += __uint_as_float((v).w & 0xffff0000u);                    \
    } while (0)

    int j = s + slot;
    for (; j + 24 < e; j += 32) {
        int i0 = idxs[j];
        int i1 = idxs[j + 8];
        int i2 = idxs[j + 16];
        int i3 = idxs[j + 24];
        uint4 v0 = fp[(size_t)i0 * 64];
        uint4 v1 = fp[(size_t)i1 * 64];
        uint4 v2 = fp[(size_t)i2 * 64];
        uint4 v3 = fp[(size_t)i3 * 64];
        ACC8(v0); ACC8(v1); ACC8(v2); ACC8(v3);
    }
    for (; j + 8 < e; j += 16) {
        int i0 = idxs[j];
        int i1 = idxs[j + 8];
        uint4 v0 = fp[(size_t)i0 * 64];
        uint4 v1 = fp[(size_t)i1 * 64];
        ACC8(v0); ACC8(v1);
    }
    for (; j < e; j += 8) {
        uint4 v = fp[(size_t)idxs[j] * 64];
        ACC8(v);
    }
#undef ACC8

    // reduce over the 8 slots (lane bits 3,4,5)
    a0 += __shfl_xor(a0, 8); a0 += __shfl_xor(a0, 16); a0 += __shfl_xor(a0, 32);
    a1 += __shfl_xor(a1, 8); a1 += __shfl_xor(a1, 16); a1 += __shfl_xor(a1, 32);
    a2 += __shfl_xor(a2, 8); a2 += __shfl_xor(a2, 16); a2 += __shfl_xor(a2, 32);
    a3 += __shfl_xor(a3, 8); a3 += __shfl_xor(a3, 16); a3 += __shfl_xor(a3, 32);
    a4 += __shfl_xor(a4, 8); a4 += __shfl_xor(a4, 16); a4 += __shfl_xor(a4, 32);
    a5 += __shfl_xor(a5, 8); a5 += __shfl_xor(a5, 16); a5 += __shfl_xor(a5, 32);
    a6 += __shfl_xor(a6, 8); a6 += __shfl_xor(a6, 16); a6 += __shfl_xor(a6, 32);
    a7 += __shfl_xor(a7, 8); a7 += __shfl_xor(a7, 16); a7 += __shfl_xor(a7, 32);

    __shared__ float tile[4][64];
    if (slot == 0) {
        float cf = (float)(cnt > 0 ? cnt : 1);
        int bl = lane_b * 8;
        tile[wave][bl + 0] = a0 / cf;
        tile[wave][bl + 1] = a1 / cf;
        tile[wave][bl + 2] = a2 / cf;
        tile[wave][bl + 3] = a3 / cf;
        tile[wave][bl + 4] = a4 / cf;
        tile[wave][bl + 5] = a5 / cf;
        tile[wave][bl + 6] = a6 / cf;
        tile[wave][bl + 7] = a7 / cf;
    }
    __syncthreads();

    // direct store to out (B,G): thread t -> b_local = t>>2, gi = t&3
    int b_local = threadIdx.x >> 2;
    int gi      = threadIdx.x & 3;
    int gg      = (blockIdx.x >> 3) * 4 + gi;
    out[(size_t)(chunk * 64 + b_local) * G + gg] = tile[gi][b_local];
}

// Fallback for unexpected shapes (correct but slow).
__global__ __launch_bounds__(256) void pa_group_mean_direct(
    const float* __restrict__ feat, const int* __restrict__ flat_indices,
    const int* __restrict__ segment_ids, float* __restrict__ out,
    int T, int B, int N, int G) {
    const int g = blockIdx.x;
    const int tid = threadIdx.x;
    __shared__ int sb[2];
    __shared__ int s_idx[256];
    if (tid < 2) {
        int target = g + tid;
        int lo = 0, hi = T;
        while (lo < hi) {
            int mid = (lo + hi) >> 1;
            if (segment_ids[mid] < target) lo = mid + 1; else hi = mid;
        }
        sb[tid] = lo;
    }
    __syncthreads();
    const int s = sb[0], e = sb[1];
    const int cnt = e - s;
    int b0 = tid * 2, b1 = tid * 2 + 1;
    float x0 = 0.f, x1 = 0.f;
    for (int base = s; base < e; base += 256) {
        int k = base + tid;
        if (k < e) s_idx[tid] = flat_indices[k];
        __syncthreads();
        int m = min(256, e - base);
        for (int jj = 0; jj < m; ++jj) {
            int idx = s_idx[jj];
            if (b0 < B) x0 += feat[(long)b0 * N + idx];
            if (b1 < B) x1 += feat[(long)b1 * N + idx];
        }
        __syncthreads();
    }
    float inv = 1.0f / (float)(cnt > 0 ? cnt : 1);
    if (b0 < B) out[(long)b0 * G + g] = x0 * inv;
    if (b1 < B) out[(long)b1 * G + g] = x1 * inv;
}

extern "C" void kernel_launch(void* const* d_in, const int* in_sizes, int n_in,
                              void* d_out, int out_size, void* d_ws, size_t ws_size,
                              hipStream_t stream) {
    const float* feat          = (const float*)d_in[0];
    const int*   flat_indices  = (const int*)d_in[1];
    const int*   segment_ids   = (const int*)d_in[2];
    float*       out           = (float*)d_out;

    const int B = 512;
    const int N = in_sizes[0] / B;      // 10000
    const int T = in_sizes[1];          // 131072
    const int G = out_size / B;         // 2048

    size_t featT_bytes = (size_t)N * B * sizeof(unsigned short);
    size_t need = featT_bytes + (size_t)(G + 1) * sizeof(int);
    if (ws_size >= need && B == 512 && (G % 4) == 0 && T >= 1) {
        unsigned short* featT = (unsigned short*)d_ws;            // (N, 512) bf16
        int* offs = (int*)((char*)d_ws + featT_bytes);            // (G+1,)

        pa_offsets_linear<<<(T + 255) / 256, 256, 0, stream>>>(segment_ids, offs, T, G);

        dim3 blk(32, 8);
        dim3 g1((N + TRN - 1) / TRN, B / TRB);
        pa_transpose_bf16<<<g1, blk, 0, stream>>>(feat, featT, N);

        pa_gather_mean_bf16<<<(G / 4) * 8, 256, 0, stream>>>(featT, flat_indices, offs,
                                                             out, G);
    } else {
        pa_group_mean_direct<<<G, 256, 0, stream>>>(feat, flat_indices, segment_ids,
                                                    out, T, B, N, G);
    }
}

// Round 4
// 27.993 us; speedup vs baseline: 2.0015x; 1.2025x over previous
//
#include <hip/hip_runtime.h>

// PoolingAggregator: out[b,g] = mean over {t : segment_ids[t]==g} of feat[b, flat_indices[t]]
// B=512, N=10000, G=2048, T=131072.
//
// Pipeline (2 kernels):
//   k1 "prep": grid (157, 9).
//       y<8 : transpose+convert feat (B,N) f32 -> featT (N,512) bf16, 64x64 tiles,
//             float4 reads (16B/lane), uint2 bf16 writes.
//       y==8: offs[g] = lower_bound(segment_ids, g) via linear boundary scan
//             (runs concurrently with the transpose blocks in the same dispatch).
//   k2 "gather": one WAVE per (group, 64-float B-chunk); chunk = blockIdx%8 pins each
//       1.28MB featT slice to one XCD L2. Per 64-index window: ONE coalesced index
//       load (lane t <- idxs[w+t]), then 8 independent 1KB row loads per wave with
//       addresses via __shfl (no idx->data dependent chain). shfl_xor slot reduce,
//       LDS 4x64 tile, direct coalesced store to out (B,G).

__device__ __forceinline__ unsigned bf16rne(float f) {
    unsigned u = __float_as_uint(f);
    return (u + 0x7fffu + ((u >> 16) & 1u)) >> 16;
}

// grid (ceil(N/64), 9), 256 threads.
__global__ __launch_bounds__(256) void pa_prep(const float* __restrict__ feat,
                                               const int* __restrict__ seg,
                                               unsigned short* __restrict__ featT,
                                               int* __restrict__ offs,
                                               int N, int T, int G, int nXBlocks) {
    if (blockIdx.y == 8) {
        // ---- offsets: linear boundary scan over sorted seg ----
        int stride = nXBlocks * 256;
        for (int t = blockIdx.x * 256 + threadIdx.x; t < T; t += stride) {
            int cur  = seg[t];
            int prev = (t == 0) ? -1 : seg[t - 1];
            for (int g = prev + 1; g <= cur; ++g) offs[g] = t;
            if (t == T - 1) {
                for (int g = cur + 1; g <= G; ++g) offs[g] = T;
            }
        }
        return;
    }

    // ---- transpose 64(b) x 64(n) tile ----
    __shared__ float tile[64][65];
    const int n0 = blockIdx.x * 64;
    const int b0 = blockIdx.y * 64;
    const int tid = threadIdx.x;
    const int r  = tid >> 4;   // 0..15
    const int c4 = tid & 15;   // float4 column

    if ((N & 3) == 0 && n0 + 64 <= N) {
        #pragma unroll
        for (int i = 0; i < 4; ++i) {
            int b = r + 16 * i;
            const float4 v = *(const float4*)&feat[(size_t)(b0 + b) * N + n0 + c4 * 4];
            tile[b][c4 * 4 + 0] = v.x;
            tile[b][c4 * 4 + 1] = v.y;
            tile[b][c4 * 4 + 2] = v.z;
            tile[b][c4 * 4 + 3] = v.w;
        }
    } else {
        #pragma unroll
        for (int i = 0; i < 4; ++i) {
            int b = r + 16 * i;
            #pragma unroll
            for (int j = 0; j < 4; ++j) {
                int n = n0 + c4 * 4 + j;
                tile[b][c4 * 4 + j] = (n < N) ? feat[(size_t)(b0 + b) * N + n] : 0.0f;
            }
        }
    }
    __syncthreads();

    uint2* outu = (uint2*)featT;  // row = 128 uint2 (512 bf16)
    #pragma unroll
    for (int i = 0; i < 4; ++i) {
        int nl = r + 16 * i;
        int n = n0 + nl;
        if (n >= N) continue;
        float f0 = tile[c4 * 4 + 0][nl];
        float f1 = tile[c4 * 4 + 1][nl];
        float f2 = tile[c4 * 4 + 2][nl];
        float f3 = tile[c4 * 4 + 3][nl];
        uint2 u;
        u.x = bf16rne(f0) | (bf16rne(f1) << 16);
        u.y = bf16rne(f2) | (bf16rne(f3) << 16);
        outu[(size_t)n * 128 + (b0 >> 2) + c4] = u;
    }
}

// grid = (G/4)*8 blocks, 256 threads (4 waves). Wave w of block b: group (b>>3)*4+w,
// B-chunk c = b&7 (64 floats = 8 lanes x 8 bf16), slot = lane>>3 (8 index-parallel).
__global__ __launch_bounds__(256) void pa_gather_mean_bf16(
    const unsigned short* __restrict__ featT,  // (N, 512) bf16
    const int* __restrict__ idxs,              // (T,)
    const int* __restrict__ offs,              // (G+1,)
    float* __restrict__ out,                   // (B, G)
    int G) {
    const int chunk = blockIdx.x & 7;
    const int wave  = threadIdx.x >> 6;
    const int g     = (blockIdx.x >> 3) * 4 + wave;
    const int lane  = threadIdx.x & 63;
    const int lane_b = lane & 7;
    const int slot   = lane >> 3;

    const int s = offs[g];
    const int e = offs[g + 1];
    const int cnt = e - s;

    // row stride = 512 bf16 = 64 uint4; lane covers 8 bf16 = 1 uint4
    const uint4* __restrict__ fp = (const uint4*)featT + chunk * 8 + lane_b;

    float a0 = 0.f, a1 = 0.f, a2 = 0.f, a3 = 0.f,
          a4 = 0.f, a5 = 0.f, a6 = 0.f, a7 = 0.f;

#define ACC8(v)                                                        \
    do {                                                               \
        a0 += __uint_as_float((v).x << 16);                            \
        a1 += __uint_as_float((v).x & 0xffff0000u);                    \
        a2 += __uint_as_float((v).y << 16);                            \
        a3 += __uint_as_float((v).y & 0xffff0000u);                    \
        a4 += __uint_as_float((v).z << 16);                            \
        a5 += __uint_as_float((v).z & 0xffff0000u);                    \
        a6 += __uint_as_float((v).w << 16);                            \
        a7 += __uint_as_float((v).w & 0xffff0000u);                    \
    } while (0)

    for (int w = s; w < e; w += 64) {
        int m = e - w;
        if (m > 64) m = 64;
        // one coalesced load: lane t holds idxs[w+t]
        int myidx = (lane < m) ? idxs[w + lane] : 0;
        // slot handles local indices slot, slot+8, ..., slot+56 (addresses via shfl)
        #pragma unroll
        for (int k = 0; k < 8; ++k) {
            int li = slot + 8 * k;
            int ridx = __shfl(myidx, li);
            if (li < m) {
                uint4 v = fp[(size_t)ridx * 64];
                ACC8(v);
            }
        }
    }
#undef ACC8

    // reduce over the 8 slots (lane bits 3,4,5)
    a0 += __shfl_xor(a0, 8); a0 += __shfl_xor(a0, 16); a0 += __shfl_xor(a0, 32);
    a1 += __shfl_xor(a1, 8); a1 += __shfl_xor(a1, 16); a1 += __shfl_xor(a1, 32);
    a2 += __shfl_xor(a2, 8); a2 += __shfl_xor(a2, 16); a2 += __shfl_xor(a2, 32);
    a3 += __shfl_xor(a3, 8); a3 += __shfl_xor(a3, 16); a3 += __shfl_xor(a3, 32);
    a4 += __shfl_xor(a4, 8); a4 += __shfl_xor(a4, 16); a4 += __shfl_xor(a4, 32);
    a5 += __shfl_xor(a5, 8); a5 += __shfl_xor(a5, 16); a5 += __shfl_xor(a5, 32);
    a6 += __shfl_xor(a6, 8); a6 += __shfl_xor(a6, 16); a6 += __shfl_xor(a6, 32);
    a7 += __shfl_xor(a7, 8); a7 += __shfl_xor(a7, 16); a7 += __shfl_xor(a7, 32);

    __shared__ float tile[4][64];
    if (slot == 0) {
        float inv = 1.0f / (float)(cnt > 0 ? cnt : 1);
        int bl = lane_b * 8;
        tile[wave][bl + 0] = a0 * inv;
        tile[wave][bl + 1] = a1 * inv;
        tile[wave][bl + 2] = a2 * inv;
        tile[wave][bl + 3] = a3 * inv;
        tile[wave][bl + 4] = a4 * inv;
        tile[wave][bl + 5] = a5 * inv;
        tile[wave][bl + 6] = a6 * inv;
        tile[wave][bl + 7] = a7 * inv;
    }
    __syncthreads();

    // store to out (B,G): thread t -> b_local = t>>2, gi = t&3 (16B per 4 threads)
    int b_local = threadIdx.x >> 2;
    int gi      = threadIdx.x & 3;
    int gg      = (blockIdx.x >> 3) * 4 + gi;
    out[(size_t)(chunk * 64 + b_local) * G + gg] = tile[gi][b_local];
}

// Fallback for unexpected shapes (correct but slow).
__global__ __launch_bounds__(256) void pa_group_mean_direct(
    const float* __restrict__ feat, const int* __restrict__ flat_indices,
    const int* __restrict__ segment_ids, float* __restrict__ out,
    int T, int B, int N, int G) {
    const int g = blockIdx.x;
    const int tid = threadIdx.x;
    __shared__ int sb[2];
    __shared__ int s_idx[256];
    if (tid < 2) {
        int target = g + tid;
        int lo = 0, hi = T;
        while (lo < hi) {
            int mid = (lo + hi) >> 1;
            if (segment_ids[mid] < target) lo = mid + 1; else hi = mid;
        }
        sb[tid] = lo;
    }
    __syncthreads();
    const int s = sb[0], e = sb[1];
    const int cnt = e - s;
    int b0 = tid * 2, b1 = tid * 2 + 1;
    float x0 = 0.f, x1 = 0.f;
    for (int base = s; base < e; base += 256) {
        int k = base + tid;
        if (k < e) s_idx[tid] = flat_indices[k];
        __syncthreads();
        int m = min(256, e - base);
        for (int jj = 0; jj < m; ++jj) {
            int idx = s_idx[jj];
            if (b0 < B) x0 += feat[(long)b0 * N + idx];
            if (b1 < B) x1 += feat[(long)b1 * N + idx];
        }
        __syncthreads();
    }
    float inv = 1.0f / (float)(cnt > 0 ? cnt : 1);
    if (b0 < B) out[(long)b0 * G + g] = x0 * inv;
    if (b1 < B) out[(long)b1 * G + g] = x1 * inv;
}

extern "C" void kernel_launch(void* const* d_in, const int* in_sizes, int n_in,
                              void* d_out, int out_size, void* d_ws, size_t ws_size,
                              hipStream_t stream) {
    const float* feat          = (const float*)d_in[0];
    const int*   flat_indices  = (const int*)d_in[1];
    const int*   segment_ids   = (const int*)d_in[2];
    float*       out           = (float*)d_out;

    const int B = 512;
    const int N = in_sizes[0] / B;      // 10000
    const int T = in_sizes[1];          // 131072
    const int G = out_size / B;         // 2048

    size_t featT_bytes = (size_t)N * B * sizeof(unsigned short);
    size_t need = featT_bytes + (size_t)(G + 1) * sizeof(int);
    if (ws_size >= need && B == 512 && (G % 4) == 0 && T >= 1) {
        unsigned short* featT = (unsigned short*)d_ws;            // (N, 512) bf16
        int* offs = (int*)((char*)d_ws + featT_bytes);            // (G+1,)

        int nXBlocks = (N + 63) / 64;  // 157
        dim3 g1(nXBlocks, 9);
        pa_prep<<<g1, 256, 0, stream>>>(feat, segment_ids, featT, offs, N, T, G, nXBlocks);

        pa_gather_mean_bf16<<<(G / 4) * 8, 256, 0, stream>>>(featT, flat_indices, offs,
                                                             out, G);
    } else {
        pa_group_mean_direct<<<G, 256, 0, stream>>>(feat, flat_indices, segment_ids,
                                                    out, T, B, N, G);
    }
}